// Round 8
// baseline (47.896 us; speedup 1.0000x reference)
//
#include <hip/hip_runtime.h>
#include <math.h>

#define DH 15
#define NNODES 64           // Chebyshev-Lobatto nodes, degree 63
#define M_DEG  63

typedef float v2f __attribute__((ext_vector_type(2)));

// ---- stable tanh + derivative factors -------------------------------------
__device__ __forceinline__ void tanh_fs(float u0, float& t, float& s,
                                        float& f2, float& f3, float& f4) {
    float e = __builtin_amdgcn_exp2f(u0 * 2.885390081777927f); // exp(2*u0)
    float r = __builtin_amdgcn_rcpf(1.0f + e);
    t = 1.0f - 2.0f * r;
    s = 4.0f * r * (1.0f - r);
    f2 = -2.0f * t * s;
    f3 = s * (4.0f * t * t - 2.0f * s);
    f4 = 8.0f * t * s * (2.0f * s - t * t);
}

__device__ __forceinline__ void tanh_jet(float u0, float u1, float u2,
                                         float u3, float u4, float h[5]) {
    float t, s, f2, f3, f4;
    tanh_fs(u0, t, s, f2, f3, f4);
    float u1s = u1 * u1;
    h[0] = t;
    h[1] = s * u1;
    h[2] = f2 * u1s + s * u2;
    h[3] = f3 * u1s * u1 + 3.0f * f2 * u1 * u2 + s * u3;
    h[4] = f4 * u1s * u1s + 6.0f * f3 * u1s * u2
         + f2 * (3.0f * u2 * u2 + 4.0f * u1 * u3) + s * u4;
}

// ---- dense 15->15 + tanh on jets, rolled loops, jet state in LDS ------------
// hs[j][c][lane]: lane-private columns (stride 4B -> 2 lanes/bank, free).
// Rolled (#pragma unroll 1) keeps unique code ~200 inst/layer (I$-resident);
// 1-ahead prefetch hides ds_read (~120cy) and s_load (~200cy) latency.
__device__ __forceinline__ void dense_layer_lds(float (*hs)[5][NNODES],
                                                const float* __restrict__ W,
                                                const float* __restrict__ B,
                                                int lane) {
    float u[DH][5];
    {   // k = 0: init u (bias added later in tanh pass)
        float h0 = hs[0][0][lane], h1 = hs[0][1][lane], h2 = hs[0][2][lane],
              h3 = hs[0][3][lane], h4 = hs[0][4][lane];
#pragma unroll
        for (int j = 0; j < DH; ++j) {
            float w = W[j];
            u[j][0] = h0 * w; u[j][1] = h1 * w; u[j][2] = h2 * w;
            u[j][3] = h3 * w; u[j][4] = h4 * w;
        }
    }
    // prefetch row 1 (h in VGPR, W row in SGPR)
    float p0 = hs[1][0][lane], p1 = hs[1][1][lane], p2 = hs[1][2][lane],
          p3 = hs[1][3][lane], p4 = hs[1][4][lane];
    float wn[DH];
#pragma unroll
    for (int j = 0; j < DH; ++j) wn[j] = W[DH + j];
#pragma unroll 1
    for (int k = 1; k < DH; ++k) {
        float h0 = p0, h1 = p1, h2 = p2, h3 = p3, h4 = p4;
        float wc[DH];
#pragma unroll
        for (int j = 0; j < DH; ++j) wc[j] = wn[j];
        if (k + 1 < DH) {
            p0 = hs[k+1][0][lane]; p1 = hs[k+1][1][lane]; p2 = hs[k+1][2][lane];
            p3 = hs[k+1][3][lane]; p4 = hs[k+1][4][lane];
#pragma unroll
            for (int j = 0; j < DH; ++j) wn[j] = W[(k + 1) * DH + j];
        }
#pragma unroll
        for (int j = 0; j < DH; ++j) {
            float w = wc[j];
            u[j][0] = fmaf(h0, w, u[j][0]);
            u[j][1] = fmaf(h1, w, u[j][1]);
            u[j][2] = fmaf(h2, w, u[j][2]);
            u[j][3] = fmaf(h3, w, u[j][3]);
            u[j][4] = fmaf(h4, w, u[j][4]);
        }
    }
    // u -> LDS (enables runtime-j tanh pass), then in-place tanh
#pragma unroll
    for (int j = 0; j < DH; ++j)
#pragma unroll
        for (int c = 0; c < 5; ++c) hs[j][c][lane] = u[j][c];

    float q0 = hs[0][0][lane], q1 = hs[0][1][lane], q2 = hs[0][2][lane],
          q3 = hs[0][3][lane], q4 = hs[0][4][lane];
    float bnx = B[0];
#pragma unroll 1
    for (int j = 0; j < DH; ++j) {
        float u0 = q0 + bnx, u1 = q1, u2 = q2, u3 = q3, u4 = q4;
        if (j + 1 < DH) {
            q0 = hs[j+1][0][lane]; q1 = hs[j+1][1][lane]; q2 = hs[j+1][2][lane];
            q3 = hs[j+1][3][lane]; q4 = hs[j+1][4][lane];
            bnx = B[j + 1];
        }
        float hj[5];
        tanh_jet(u0, u1, u2, u3, u4, hj);
        hs[j][0][lane] = hj[0]; hs[j][1][lane] = hj[1]; hs[j][2][lane] = hj[2];
        hs[j][3][lane] = hj[3]; hs[j][4][lane] = hj[4];
    }
}

// ---- kernel A: exact jets at 64 Chebyshev-Lobatto nodes -> DCT-I coeffs -----
// lane j: x_j = (1+cos(pi*j/63))/2 (lane 0 -> x=1, lane 63 -> x=0, exact).
__global__ void __launch_bounds__(64)
pinn_nodes(const float* __restrict__ W1, const float* __restrict__ b1,
           const float* __restrict__ W2, const float* __restrict__ b2,
           const float* __restrict__ W3, const float* __restrict__ b3,
           const float* __restrict__ W4, const float* __restrict__ b4,
           float* __restrict__ C, float* __restrict__ bc) {
    __shared__ float hs[DH][5][NNODES];
    __shared__ alignas(16) float rsh[NNODES];
    const int lane = threadIdx.x;        // 0..63: node index AND coeff index

    float xv;
    if (lane == 0)           xv = 1.0f;
    else if (lane == M_DEG)  xv = 0.0f;
    else xv = 0.5f + 0.5f * __builtin_amdgcn_cosf((float)lane * (1.0f / 126.0f));

    // layer 1 (rolled, W1/b1 prefetched 1 ahead)
    {
        float wnx = W1[0], bn1 = b1[0];
#pragma unroll 1
        for (int j = 0; j < DH; ++j) {
            float w = wnx, b = bn1;
            if (j + 1 < DH) { wnx = W1[j + 1]; bn1 = b1[j + 1]; }
            float t, s, f2, f3, f4;
            tanh_fs(fmaf(xv, w, b), t, s, f2, f3, f4);
            float w2 = w * w;
            hs[j][0][lane] = t;
            hs[j][1][lane] = s * w;
            hs[j][2][lane] = f2 * w2;
            hs[j][3][lane] = f3 * w2 * w;
            hs[j][4][lane] = f4 * w2 * w2;
        }
    }
    dense_layer_lds(hs, W2, b2, lane);
    dense_layer_lds(hs, W3, b3, lane);

    // output layer: all 5 jet components (rolled, prefetched)
    float o0 = b4[0], o1 = 0.f, o2 = 0.f, o3 = 0.f, o4 = 0.f;
    {
        float w4n = W4[0];
        float g0 = hs[0][0][lane], g1 = hs[0][1][lane], g2 = hs[0][2][lane],
              g3 = hs[0][3][lane], g4 = hs[0][4][lane];
#pragma unroll 1
        for (int k = 0; k < DH; ++k) {
            float w = w4n, t0 = g0, t1 = g1, t2 = g2, t3 = g3, t4 = g4;
            if (k + 1 < DH) {
                w4n = W4[k + 1];
                g0 = hs[k+1][0][lane]; g1 = hs[k+1][1][lane];
                g2 = hs[k+1][2][lane]; g3 = hs[k+1][3][lane];
                g4 = hs[k+1][4][lane];
            }
            o0 = fmaf(t0, w, o0); o1 = fmaf(t1, w, o1); o2 = fmaf(t2, w, o2);
            o3 = fmaf(t3, w, o3); o4 = fmaf(t4, w, o4);
        }
    }

    // residual with DCT end-weights folded in
    rsh[lane] = ((lane == 0 || lane == M_DEG) ? 0.5f : 1.0f) * (o4 + 1.0f);
    if (lane == M_DEG) {                  // x = 0 (left)
        bc[0] = o0; bc[1] = o1; bc[2] = o2; bc[3] = o3; bc[4] = o4;
    }
    if (lane == 0) {                      // x = 1 (right)
        bc[5] = o0; bc[6] = o1; bc[7] = o2; bc[8] = o3; bc[9] = o4;
    }
    __syncthreads();

    // residuals -> registers (broadcast b128 reads), then unrolled DCT with
    // phase accumulation: cos arg in revolutions, kept in [0,1) by cond-sub.
    float rs[NNODES];
#pragma unroll
    for (int i = 0; i < NNODES / 4; ++i) {
        float4 q = *reinterpret_cast<const float4*>(&rsh[4 * i]);
        rs[4*i] = q.x; rs[4*i+1] = q.y; rs[4*i+2] = q.z; rs[4*i+3] = q.w;
    }
    float kstep = (float)lane * (1.0f / 126.0f);
    float ph = 0.f;
    float a0 = 0.f, a1 = 0.f, a2 = 0.f, a3 = 0.f;
#pragma unroll
    for (int jj = 0; jj < NNODES; ++jj) {
        float cv = __builtin_amdgcn_cosf(ph);
        ph += kstep;
        ph = (ph >= 1.0f) ? ph - 1.0f : ph;
        float v = rs[jj] * cv;
        if ((jj & 3) == 0) a0 += v;
        else if ((jj & 3) == 1) a1 += v;
        else if ((jj & 3) == 2) a2 += v;
        else a3 += v;
    }
    float e = ((a0 + a1) + (a2 + a3)) * (2.0f / 63.0f);
    if (lane == 0 || lane == M_DEG) e *= 0.5f;
    C[lane] = e;
}

// ---- kernel B: per-point Clenshaw (degree 63), reduce residual^2 ------------
__global__ void __launch_bounds__(256)
pinn_pde(const float* __restrict__ x, const float* __restrict__ Cc,
         double* __restrict__ partials, int N) {
    // coefficients: wave-uniform loads with compile-time indices -> SGPRs
    float e[NNODES];
#pragma unroll
    for (int k = 0; k < NNODES; ++k) e[k] = Cc[k];

    int tid = threadIdx.x;
    v2f accA = {0.f, 0.f}, accB = {0.f, 0.f};
    int i0 = blockIdx.x * blockDim.x + tid;
    int gsz = gridDim.x * blockDim.x;
    int n4 = N >> 2;
    const float4* x4 = reinterpret_cast<const float4*>(x);
    for (int i = i0; i < n4; i += gsz) {
        float4 xv = x4[i];
        v2f tA = {2.f * xv.x - 1.f, 2.f * xv.y - 1.f};
        v2f tB = {2.f * xv.z - 1.f, 2.f * xv.w - 1.f};
        v2f t2A = tA + tA, t2B = tB + tB;
        v2f b0A = {0.f, 0.f}, b1A = {0.f, 0.f};
        v2f b0B = {0.f, 0.f}, b1B = {0.f, 0.f};
#pragma unroll
        for (int k = M_DEG; k >= 1; --k) {
            v2f ek = {e[k], e[k]};
            v2f bnA = __builtin_elementwise_fma(t2A, b0A, ek) - b1A;
            b1A = b0A; b0A = bnA;
            v2f bnB = __builtin_elementwise_fma(t2B, b0B, ek) - b1B;
            b1B = b0B; b0B = bnB;
        }
        v2f e0 = {e[0], e[0]};
        v2f rA = __builtin_elementwise_fma(tA, b0A, e0) - b1A;
        v2f rB = __builtin_elementwise_fma(tB, b0B, e0) - b1B;
        accA = __builtin_elementwise_fma(rA, rA, accA);
        accB = __builtin_elementwise_fma(rB, rB, accB);
    }
    float accs = (accA.x + accA.y) + (accB.x + accB.y);
    // scalar tail (N % 4 != 0)
    for (int i = (n4 << 2) + i0; i < N; i += gsz) {
        float t = 2.f * x[i] - 1.f, t2 = t + t;
        float b0 = 0.f, b1 = 0.f;
#pragma unroll
        for (int k = M_DEG; k >= 1; --k) {
            float bn = fmaf(t2, b0, e[k]) - b1;
            b1 = b0; b0 = bn;
        }
        float r = fmaf(t, b0, e[0]) - b1;
        accs = fmaf(r, r, accs);
    }

    double a = (double)accs;
#pragma unroll
    for (int off = 32; off > 0; off >>= 1) a += __shfl_down(a, off, 64);
    __shared__ double red[4];
    int lane = tid & 63, wid = tid >> 6;
    if (lane == 0) red[wid] = a;
    __syncthreads();
    if (tid == 0) partials[blockIdx.x] = red[0] + red[1] + red[2] + red[3];
}

// ---- finish: reduce partials, combine with BC jets, write scalars -----------
__global__ void __launch_bounds__(256)
pinn_finish(const double* __restrict__ partials, int nparts,
            const float* __restrict__ bc,
            float* __restrict__ out, int N, float* __restrict__ consts) {
    int tid = threadIdx.x;
    double a = 0.0;
    for (int i = tid; i < nparts; i += 256) a += partials[i];
#pragma unroll
    for (int off = 32; off > 0; off >>= 1) a += __shfl_down(a, off, 64);
    __shared__ double red[4];
    if ((tid & 63) == 0) red[tid >> 6] = a;
    __syncthreads();
    if (tid == 0) {
        double total = red[0] + red[1] + red[2] + red[3];
        float pdef = (float)(total / (double)N);
        float lbw  = bc[0] * bc[0];   // w(0)^2
        float lbwx = bc[1] * bc[1];   // w_x(0)^2
        float rbM  = bc[7] * bc[7];   // w_xx(1)^2
        float rbw  = bc[5] * bc[5];   // w(1)^2
        float loss = pdef + lbw + lbwx + rbM + rbw;  // reference add order
        consts[0] = loss; consts[1] = lbw; consts[2] = lbwx;
        consts[3] = rbM;  consts[4] = rbw;
        out[N] = pdef;   // pde_loss scalar
    }
}

// ---- fill: broadcast 5 constants into their [N] regions ---------------------
__global__ void __launch_bounds__(256)
pinn_fill(float* __restrict__ out, const float* __restrict__ consts, int N) {
    int r = blockIdx.y;                       // 0:loss 1:lbw 2:lbwx 3:rbM 4:rbw
    float c = consts[r];
    size_t base = (r == 0) ? 0 : ((size_t)r * (size_t)N + 1);
    float* p = out + base;
    size_t tid = (size_t)blockIdx.x * blockDim.x + threadIdx.x;
    size_t stride = (size_t)gridDim.x * blockDim.x;
    size_t head = ((16 - ((size_t)p & 15)) & 15) >> 2;  // floats to 16B align
    size_t n = (size_t)N;
    if (head > n) head = n;
    if (tid < head) p[tid] = c;
    size_t n4 = (n - head) >> 2;
    float4* p4 = reinterpret_cast<float4*>(p + head);
    float4 cv = {c, c, c, c};
    for (size_t i = tid; i < n4; i += stride) p4[i] = cv;
    size_t done = head + (n4 << 2);
    size_t t = done + tid;
    if (t < n) p[t] = c;
}

extern "C" void kernel_launch(void* const* d_in, const int* in_sizes, int n_in,
                              void* d_out, int out_size, void* d_ws, size_t ws_size,
                              hipStream_t stream) {
    const float* x  = (const float*)d_in[0];
    const float* W1 = (const float*)d_in[1];
    const float* b1 = (const float*)d_in[2];
    const float* W2 = (const float*)d_in[3];
    const float* b2 = (const float*)d_in[4];
    const float* W3 = (const float*)d_in[5];
    const float* b3 = (const float*)d_in[6];
    const float* W4 = (const float*)d_in[7];
    const float* b4 = (const float*)d_in[8];
    float* out = (float*)d_out;
    int N = in_sizes[0];

    // ws layout: C[64] @0 | bc[10] @256B | consts[8] @384B | partials @1024B
    float*  C        = (float*)d_ws;
    float*  bc       = (float*)((char*)d_ws + 256);
    float*  consts   = (float*)((char*)d_ws + 384);
    double* partials = (double*)((char*)d_ws + 1024);

    int NB = 512;
    size_t need = 1024 + (size_t)NB * 8;
    if (ws_size < need) {
        NB = (int)((ws_size > 1024 + 8) ? (ws_size - 1024) / 8 : 1);
        if (NB < 1) NB = 1;
        if (NB > 512) NB = 512;
    }

    hipLaunchKernelGGL(pinn_nodes, dim3(1), dim3(64), 0, stream,
                       W1, b1, W2, b2, W3, b3, W4, b4, C, bc);
    hipLaunchKernelGGL(pinn_pde, dim3(NB), dim3(256), 0, stream,
                       x, C, partials, N);
    hipLaunchKernelGGL(pinn_finish, dim3(1), dim3(256), 0, stream,
                       partials, NB, bc, out, N, consts);
    int gx = (N / 4 + 255) / 256;
    if (gx > 1024) gx = 1024;
    if (gx < 1) gx = 1;
    hipLaunchKernelGGL(pinn_fill, dim3(gx, 5), dim3(256), 0, stream,
                       out, consts, N);
}

// Round 9
// 31.870 us; speedup vs baseline: 1.5028x; 1.5028x over previous
//
#include <hip/hip_runtime.h>
#include <math.h>

#define DH 15
#define NNODES 64           // Chebyshev-Lobatto nodes, degree 63
#define M_DEG  63

typedef float v2f __attribute__((ext_vector_type(2)));

// ---- stable tanh + derivative factors -------------------------------------
__device__ __forceinline__ void tanh_fs(float u0, float& t, float& s,
                                        float& f2, float& f3, float& f4) {
    float e = __builtin_amdgcn_exp2f(u0 * 2.885390081777927f); // exp(2*u0)
    float r = __builtin_amdgcn_rcpf(1.0f + e);
    t = 1.0f - 2.0f * r;
    s = 4.0f * r * (1.0f - r);
    f2 = -2.0f * t * s;
    f3 = s * (4.0f * t * t - 2.0f * s);
    f4 = 8.0f * t * s * (2.0f * s - t * t);
}

__device__ __forceinline__ void tanh_jet(float u0, float u1, float u2,
                                         float u3, float u4, float h[5]) {
    float t, s, f2, f3, f4;
    tanh_fs(u0, t, s, f2, f3, f4);
    float u1s = u1 * u1;
    h[0] = t;
    h[1] = s * u1;
    h[2] = f2 * u1s + s * u2;
    h[3] = f3 * u1s * u1 + 3.0f * f2 * u1 * u2 + s * u3;
    h[4] = f4 * u1s * u1s + 6.0f * f3 * u1s * u2
         + f2 * (3.0f * u2 * u2 + 4.0f * u1 * u3) + s * u4;
}

// ---- kernel A: 4-wave cooperative jet eval at 64 nodes -> DCT-I coeffs ------
// lane = node (0..63), wq = threadIdx.x>>6 = j-quad (wave-uniform).
// Jet state hs[j][c][node]: lane-indexed inner dim -> 2 lanes/bank, free.
// Each wave owns output neurons j = wq*4..wq*4+3 (j=15 dropped).
__global__ void __launch_bounds__(256)
pinn_nodes(const float* __restrict__ W1, const float* __restrict__ b1,
           const float* __restrict__ W2, const float* __restrict__ b2,
           const float* __restrict__ W3, const float* __restrict__ b3,
           const float* __restrict__ W4, const float* __restrict__ b4,
           float* __restrict__ C, float* __restrict__ bc) {
    __shared__ float hs[DH][5][NNODES];
    __shared__ alignas(16) float rsh[NNODES];
    const int tid  = threadIdx.x;
    const int lane = tid & 63;           // node index
    const int wq   = tid >> 6;           // j-quad (wave-uniform)

    float xv;
    if (lane == 0)           xv = 1.0f;
    else if (lane == M_DEG)  xv = 0.0f;
    else xv = 0.5f + 0.5f * __builtin_amdgcn_cosf((float)lane * (1.0f / 126.0f));

    // layer 1: each wave computes its 4 neurons
#pragma unroll
    for (int jj = 0; jj < 4; ++jj) {
        int j = wq * 4 + jj;
        if (j < DH) {
            float w = W1[j];
            float t, s, f2, f3, f4;
            tanh_fs(fmaf(xv, w, b1[j]), t, s, f2, f3, f4);
            float w2 = w * w;
            hs[j][0][lane] = t;
            hs[j][1][lane] = s * w;
            hs[j][2][lane] = f2 * w2;
            hs[j][3][lane] = f3 * w2 * w;
            hs[j][4][lane] = f4 * w2 * w2;
        }
    }
    __syncthreads();

    // layers 2 and 3: u[jj][c] = sum_k hs[k][c][node] * W[k*15 + j]
    const float* Ws[2] = {W2, W3};
    const float* Bs[2] = {b2, b3};
#pragma unroll
    for (int L = 0; L < 2; ++L) {
        const float* W = Ws[L];
        const float* B = Bs[L];
        float u[4][5];
#pragma unroll
        for (int jj = 0; jj < 4; ++jj)
#pragma unroll
            for (int c = 0; c < 5; ++c) u[jj][c] = 0.f;
#pragma unroll
        for (int k = 0; k < DH; ++k) {
            float g0 = hs[k][0][lane], g1 = hs[k][1][lane], g2 = hs[k][2][lane],
                  g3 = hs[k][3][lane], g4 = hs[k][4][lane];
#pragma unroll
            for (int jj = 0; jj < 4; ++jj) {
                int j = wq * 4 + jj;
                float w = (j < DH) ? W[k * DH + j] : 0.f;
                u[jj][0] = fmaf(g0, w, u[jj][0]);
                u[jj][1] = fmaf(g1, w, u[jj][1]);
                u[jj][2] = fmaf(g2, w, u[jj][2]);
                u[jj][3] = fmaf(g3, w, u[jj][3]);
                u[jj][4] = fmaf(g4, w, u[jj][4]);
            }
        }
        __syncthreads();   // all reads of hs done before overwrite
#pragma unroll
        for (int jj = 0; jj < 4; ++jj) {
            int j = wq * 4 + jj;
            if (j < DH) {
                float hj[5];
                tanh_jet(u[jj][0] + B[j], u[jj][1], u[jj][2], u[jj][3],
                         u[jj][4], hj);
                hs[j][0][lane] = hj[0]; hs[j][1][lane] = hj[1];
                hs[j][2][lane] = hj[2]; hs[j][3][lane] = hj[3];
                hs[j][4][lane] = hj[4];
            }
        }
        __syncthreads();
    }

    // output layer + residual + bc: wave 0 only (all barriers already passed)
    if (wq == 0) {
        float o0 = b4[0], o1 = 0.f, o2 = 0.f, o3 = 0.f, o4 = 0.f;
#pragma unroll
        for (int k = 0; k < DH; ++k) {
            float w = W4[k];
            o0 = fmaf(hs[k][0][lane], w, o0);
            o1 = fmaf(hs[k][1][lane], w, o1);
            o2 = fmaf(hs[k][2][lane], w, o2);
            o3 = fmaf(hs[k][3][lane], w, o3);
            o4 = fmaf(hs[k][4][lane], w, o4);
        }
        // residual with DCT end-weights folded in
        rsh[lane] = ((lane == 0 || lane == M_DEG) ? 0.5f : 1.0f) * (o4 + 1.0f);
        if (lane == M_DEG) {                  // x = 0 (left)
            bc[0] = o0; bc[1] = o1; bc[2] = o2; bc[3] = o3; bc[4] = o4;
        }
        if (lane == 0) {                      // x = 1 (right)
            bc[5] = o0; bc[6] = o1; bc[7] = o2; bc[8] = o3; bc[9] = o4;
        }
        // wave-level fence: rsh written by this wave, read below by this wave
        __builtin_amdgcn_s_waitcnt(0);

        // DCT-I: c_k = (2/63) sum'' r_j cos(pi jk/63); v_cos arg in revolutions,
        // phase accumulation with conditional wrap (exact enough: |err|~1e-6).
        float rs[NNODES];
#pragma unroll
        for (int i = 0; i < NNODES / 4; ++i) {
            float4 q = *reinterpret_cast<const float4*>(&rsh[4 * i]);
            rs[4*i] = q.x; rs[4*i+1] = q.y; rs[4*i+2] = q.z; rs[4*i+3] = q.w;
        }
        float kstep = (float)lane * (1.0f / 126.0f);
        float ph = 0.f;
        float a0 = 0.f, a1 = 0.f, a2 = 0.f, a3 = 0.f;
#pragma unroll
        for (int jj = 0; jj < NNODES; ++jj) {
            float cv = __builtin_amdgcn_cosf(ph);
            ph += kstep;
            ph = (ph >= 1.0f) ? ph - 1.0f : ph;
            float v = rs[jj] * cv;
            if ((jj & 3) == 0) a0 += v;
            else if ((jj & 3) == 1) a1 += v;
            else if ((jj & 3) == 2) a2 += v;
            else a3 += v;
        }
        float e = ((a0 + a1) + (a2 + a3)) * (2.0f / 63.0f);
        if (lane == 0 || lane == M_DEG) e *= 0.5f;
        C[lane] = e;
    }
}

// ---- helper: grid-stride constant fill of one [N] region --------------------
__device__ __forceinline__ void fill_region(float* __restrict__ p, float c,
                                            size_t n, size_t tid, size_t stride) {
    size_t head = ((16 - ((size_t)p & 15)) & 15) >> 2;  // floats to 16B align
    if (head > n) head = n;
    if (tid < head) p[tid] = c;
    size_t n4 = (n - head) >> 2;
    float4* p4 = reinterpret_cast<float4*>(p + head);
    float4 cv = {c, c, c, c};
    for (size_t i = tid; i < n4; i += stride) p4[i] = cv;
    size_t t = head + (n4 << 2) + tid;
    if (t < n) p[t] = c;
}

// ---- kernel B: per-point Clenshaw (degree 63), reduce residual^2,
// ---- fused with the 4 BC-region fills (stores overlap the VALU work) --------
__global__ void __launch_bounds__(256)
pinn_pde(const float* __restrict__ x, const float* __restrict__ Cc,
         const float* __restrict__ bc, float* __restrict__ out,
         double* __restrict__ partials, int N) {
    // coefficients: wave-uniform loads with compile-time indices -> SGPRs
    float e[NNODES];
#pragma unroll
    for (int k = 0; k < NNODES; ++k) e[k] = Cc[k];

    int tid = threadIdx.x;
    size_t gtid = (size_t)blockIdx.x * blockDim.x + tid;
    size_t gstride = (size_t)gridDim.x * blockDim.x;

    // fused BC fills: regions 1..4 (depend only on bc)
    {
        float lbw  = bc[0] * bc[0];
        float lbwx = bc[1] * bc[1];
        float rbM  = bc[7] * bc[7];
        float rbw  = bc[5] * bc[5];
        fill_region(out + (size_t)1 * N + 1, lbw,  (size_t)N, gtid, gstride);
        fill_region(out + (size_t)2 * N + 1, lbwx, (size_t)N, gtid, gstride);
        fill_region(out + (size_t)3 * N + 1, rbM,  (size_t)N, gtid, gstride);
        fill_region(out + (size_t)4 * N + 1, rbw,  (size_t)N, gtid, gstride);
    }

    v2f accA = {0.f, 0.f}, accB = {0.f, 0.f};
    int i0 = (int)gtid;
    int gsz = (int)gstride;
    int n4 = N >> 2;
    const float4* x4 = reinterpret_cast<const float4*>(x);
    for (int i = i0; i < n4; i += gsz) {
        float4 xv = x4[i];
        v2f tA = {2.f * xv.x - 1.f, 2.f * xv.y - 1.f};
        v2f tB = {2.f * xv.z - 1.f, 2.f * xv.w - 1.f};
        v2f t2A = tA + tA, t2B = tB + tB;
        v2f b0A = {0.f, 0.f}, b1A = {0.f, 0.f};
        v2f b0B = {0.f, 0.f}, b1B = {0.f, 0.f};
#pragma unroll
        for (int k = M_DEG; k >= 1; --k) {
            v2f ek = {e[k], e[k]};
            v2f bnA = __builtin_elementwise_fma(t2A, b0A, ek) - b1A;
            b1A = b0A; b0A = bnA;
            v2f bnB = __builtin_elementwise_fma(t2B, b0B, ek) - b1B;
            b1B = b0B; b0B = bnB;
        }
        v2f e0 = {e[0], e[0]};
        v2f rA = __builtin_elementwise_fma(tA, b0A, e0) - b1A;
        v2f rB = __builtin_elementwise_fma(tB, b0B, e0) - b1B;
        accA = __builtin_elementwise_fma(rA, rA, accA);
        accB = __builtin_elementwise_fma(rB, rB, accB);
    }
    float accs = (accA.x + accA.y) + (accB.x + accB.y);
    // scalar tail (N % 4 != 0)
    for (int i = (n4 << 2) + i0; i < N; i += gsz) {
        float t = 2.f * x[i] - 1.f, t2 = t + t;
        float b0 = 0.f, b1 = 0.f;
#pragma unroll
        for (int k = M_DEG; k >= 1; --k) {
            float bn = fmaf(t2, b0, e[k]) - b1;
            b1 = b0; b0 = bn;
        }
        float r = fmaf(t, b0, e[0]) - b1;
        accs = fmaf(r, r, accs);
    }

    double a = (double)accs;
#pragma unroll
    for (int off = 32; off > 0; off >>= 1) a += __shfl_down(a, off, 64);
    __shared__ double red[4];
    int lane = tid & 63, wid = tid >> 6;
    if (lane == 0) red[wid] = a;
    __syncthreads();
    if (tid == 0) partials[blockIdx.x] = red[0] + red[1] + red[2] + red[3];
}

// ---- finish: reduce partials, combine with BC jets, write scalars -----------
__global__ void __launch_bounds__(256)
pinn_finish(const double* __restrict__ partials, int nparts,
            const float* __restrict__ bc,
            float* __restrict__ out, int N, float* __restrict__ consts) {
    int tid = threadIdx.x;
    double a = 0.0;
    for (int i = tid; i < nparts; i += 256) a += partials[i];
#pragma unroll
    for (int off = 32; off > 0; off >>= 1) a += __shfl_down(a, off, 64);
    __shared__ double red[4];
    if ((tid & 63) == 0) red[tid >> 6] = a;
    __syncthreads();
    if (tid == 0) {
        double total = red[0] + red[1] + red[2] + red[3];
        float pdef = (float)(total / (double)N);
        float lbw  = bc[0] * bc[0];   // w(0)^2
        float lbwx = bc[1] * bc[1];   // w_x(0)^2
        float rbM  = bc[7] * bc[7];   // w_xx(1)^2
        float rbw  = bc[5] * bc[5];   // w(1)^2
        float loss = pdef + lbw + lbwx + rbM + rbw;  // reference add order
        consts[0] = loss;
        out[N] = pdef;   // pde_loss scalar
    }
}

// ---- fill: broadcast the loss constant into region 0 ------------------------
__global__ void __launch_bounds__(256)
pinn_fill_loss(float* __restrict__ out, const float* __restrict__ consts, int N) {
    float c = consts[0];
    size_t tid = (size_t)blockIdx.x * blockDim.x + threadIdx.x;
    size_t stride = (size_t)gridDim.x * blockDim.x;
    fill_region(out, c, (size_t)N, tid, stride);
}

extern "C" void kernel_launch(void* const* d_in, const int* in_sizes, int n_in,
                              void* d_out, int out_size, void* d_ws, size_t ws_size,
                              hipStream_t stream) {
    const float* x  = (const float*)d_in[0];
    const float* W1 = (const float*)d_in[1];
    const float* b1 = (const float*)d_in[2];
    const float* W2 = (const float*)d_in[3];
    const float* b2 = (const float*)d_in[4];
    const float* W3 = (const float*)d_in[5];
    const float* b3 = (const float*)d_in[6];
    const float* W4 = (const float*)d_in[7];
    const float* b4 = (const float*)d_in[8];
    float* out = (float*)d_out;
    int N = in_sizes[0];

    // ws layout: C[64] @0 | bc[10] @256B | consts[8] @384B | partials @1024B
    float*  C        = (float*)d_ws;
    float*  bc       = (float*)((char*)d_ws + 256);
    float*  consts   = (float*)((char*)d_ws + 384);
    double* partials = (double*)((char*)d_ws + 1024);

    int NB = 512;
    size_t need = 1024 + (size_t)NB * 8;
    if (ws_size < need) {
        NB = (int)((ws_size > 1024 + 8) ? (ws_size - 1024) / 8 : 1);
        if (NB < 1) NB = 1;
        if (NB > 512) NB = 512;
    }

    hipLaunchKernelGGL(pinn_nodes, dim3(1), dim3(256), 0, stream,
                       W1, b1, W2, b2, W3, b3, W4, b4, C, bc);
    hipLaunchKernelGGL(pinn_pde, dim3(NB), dim3(256), 0, stream,
                       x, C, bc, out, partials, N);
    hipLaunchKernelGGL(pinn_finish, dim3(1), dim3(256), 0, stream,
                       partials, NB, bc, out, N, consts);
    int gx = (N / 4 + 255) / 256;
    if (gx > 1024) gx = 1024;
    if (gx < 1) gx = 1;
    hipLaunchKernelGGL(pinn_fill_loss, dim3(gx), dim3(256), 0, stream,
                       out, consts, N);
}

// Round 10
// 29.556 us; speedup vs baseline: 1.6205x; 1.0783x over previous
//
#include <hip/hip_runtime.h>
#include <math.h>

#define DH 15
#define NNODES 64           // Chebyshev-Lobatto nodes, degree 63
#define M_DEG  63

typedef float v2f __attribute__((ext_vector_type(2)));

// ---- stable tanh + derivative factors -------------------------------------
__device__ __forceinline__ void tanh_fs(float u0, float& t, float& s,
                                        float& f2, float& f3, float& f4) {
    float e = __builtin_amdgcn_exp2f(u0 * 2.885390081777927f); // exp(2*u0)
    float r = __builtin_amdgcn_rcpf(1.0f + e);
    t = 1.0f - 2.0f * r;
    s = 4.0f * r * (1.0f - r);
    f2 = -2.0f * t * s;
    f3 = s * (4.0f * t * t - 2.0f * s);
    f4 = 8.0f * t * s * (2.0f * s - t * t);
}

__device__ __forceinline__ void tanh_jet(float u0, float u1, float u2,
                                         float u3, float u4, float h[5]) {
    float t, s, f2, f3, f4;
    tanh_fs(u0, t, s, f2, f3, f4);
    float u1s = u1 * u1;
    h[0] = t;
    h[1] = s * u1;
    h[2] = f2 * u1s + s * u2;
    h[3] = f3 * u1s * u1 + 3.0f * f2 * u1 * u2 + s * u3;
    h[4] = f4 * u1s * u1s + 6.0f * f3 * u1s * u2
         + f2 * (3.0f * u2 * u2 + 4.0f * u1 * u3) + s * u4;
}

// ---- helper: grid-stride constant fill of one [N] region --------------------
__device__ __forceinline__ void fill_region(float* __restrict__ p, float c,
                                            size_t n, size_t tid, size_t stride) {
    size_t head = ((16 - ((size_t)p & 15)) & 15) >> 2;  // floats to 16B align
    if (head > n) head = n;
    if (tid < head) p[tid] = c;
    size_t n4 = (n - head) >> 2;
    float4* p4 = reinterpret_cast<float4*>(p + head);
    float4 cv = {c, c, c, c};
    for (size_t i = tid; i < n4; i += stride) p4[i] = cv;
    size_t t = head + (n4 << 2) + tid;
    if (t < n) p[t] = c;
}

// ---- K1: redundant 4-wave node eval + DCT per block, then fills + Clenshaw --
// Every block computes the same 64-node jet/DCT (parallel copies, ~same wall
// time as one); removes 2 dispatch boundaries and the global C handoff.
__global__ void __launch_bounds__(256)
pinn_main(const float* __restrict__ x,
          const float* __restrict__ W1, const float* __restrict__ b1,
          const float* __restrict__ W2, const float* __restrict__ b2,
          const float* __restrict__ W3, const float* __restrict__ b3,
          const float* __restrict__ W4, const float* __restrict__ b4,
          float* __restrict__ out, float* __restrict__ bcg,
          double* __restrict__ partials, int N) {
    __shared__ float hs[DH][5][NNODES];
    __shared__ alignas(16) float rsh[NNODES];
    __shared__ float C_lds[NNODES];
    __shared__ float bc_lds[10];
    const int tid  = threadIdx.x;
    const int lane = tid & 63;           // node index
    const int wq   = tid >> 6;           // j-quad (wave-uniform)

    // ===================== nodes phase (every block) =========================
    float xv;
    if (lane == 0)           xv = 1.0f;
    else if (lane == M_DEG)  xv = 0.0f;
    else xv = 0.5f + 0.5f * __builtin_amdgcn_cosf((float)lane * (1.0f / 126.0f));

    // layer 1: each wave computes its 4 neurons
#pragma unroll
    for (int jj = 0; jj < 4; ++jj) {
        int j = wq * 4 + jj;
        if (j < DH) {
            float w = W1[j];
            float t, s, f2, f3, f4;
            tanh_fs(fmaf(xv, w, b1[j]), t, s, f2, f3, f4);
            float w2 = w * w;
            hs[j][0][lane] = t;
            hs[j][1][lane] = s * w;
            hs[j][2][lane] = f2 * w2;
            hs[j][3][lane] = f3 * w2 * w;
            hs[j][4][lane] = f4 * w2 * w2;
        }
    }
    __syncthreads();

    // layers 2 and 3
    const float* Ws[2] = {W2, W3};
    const float* Bs[2] = {b2, b3};
#pragma unroll
    for (int L = 0; L < 2; ++L) {
        const float* W = Ws[L];
        const float* B = Bs[L];
        float u[4][5];
#pragma unroll
        for (int jj = 0; jj < 4; ++jj)
#pragma unroll
            for (int c = 0; c < 5; ++c) u[jj][c] = 0.f;
#pragma unroll
        for (int k = 0; k < DH; ++k) {
            float g0 = hs[k][0][lane], g1 = hs[k][1][lane], g2 = hs[k][2][lane],
                  g3 = hs[k][3][lane], g4 = hs[k][4][lane];
#pragma unroll
            for (int jj = 0; jj < 4; ++jj) {
                int j = wq * 4 + jj;
                float w = (j < DH) ? W[k * DH + j] : 0.f;
                u[jj][0] = fmaf(g0, w, u[jj][0]);
                u[jj][1] = fmaf(g1, w, u[jj][1]);
                u[jj][2] = fmaf(g2, w, u[jj][2]);
                u[jj][3] = fmaf(g3, w, u[jj][3]);
                u[jj][4] = fmaf(g4, w, u[jj][4]);
            }
        }
        __syncthreads();
#pragma unroll
        for (int jj = 0; jj < 4; ++jj) {
            int j = wq * 4 + jj;
            if (j < DH) {
                float hj[5];
                tanh_jet(u[jj][0] + B[j], u[jj][1], u[jj][2], u[jj][3],
                         u[jj][4], hj);
                hs[j][0][lane] = hj[0]; hs[j][1][lane] = hj[1];
                hs[j][2][lane] = hj[2]; hs[j][3][lane] = hj[3];
                hs[j][4][lane] = hj[4];
            }
        }
        __syncthreads();
    }

    // output layer + residual + DCT: wave 0 only
    if (wq == 0) {
        float o0 = b4[0], o1 = 0.f, o2 = 0.f, o3 = 0.f, o4 = 0.f;
#pragma unroll
        for (int k = 0; k < DH; ++k) {
            float w = W4[k];
            o0 = fmaf(hs[k][0][lane], w, o0);
            o1 = fmaf(hs[k][1][lane], w, o1);
            o2 = fmaf(hs[k][2][lane], w, o2);
            o3 = fmaf(hs[k][3][lane], w, o3);
            o4 = fmaf(hs[k][4][lane], w, o4);
        }
        rsh[lane] = ((lane == 0 || lane == M_DEG) ? 0.5f : 1.0f) * (o4 + 1.0f);
        if (lane == M_DEG) {                  // x = 0 (left)
            bc_lds[0] = o0; bc_lds[1] = o1; bc_lds[2] = o2;
            bc_lds[3] = o3; bc_lds[4] = o4;
            if (blockIdx.x == 0) {
                bcg[0] = o0; bcg[1] = o1; bcg[2] = o2; bcg[3] = o3; bcg[4] = o4;
            }
        }
        if (lane == 0) {                      // x = 1 (right)
            bc_lds[5] = o0; bc_lds[6] = o1; bc_lds[7] = o2;
            bc_lds[8] = o3; bc_lds[9] = o4;
            if (blockIdx.x == 0) {
                bcg[5] = o0; bcg[6] = o1; bcg[7] = o2; bcg[8] = o3; bcg[9] = o4;
            }
        }
        __builtin_amdgcn_s_waitcnt(0);  // wave-level fence on rsh

        // DCT-I, v_cos in revolutions, phase accumulation w/ conditional wrap
        float rs[NNODES];
#pragma unroll
        for (int i = 0; i < NNODES / 4; ++i) {
            float4 q = *reinterpret_cast<const float4*>(&rsh[4 * i]);
            rs[4*i] = q.x; rs[4*i+1] = q.y; rs[4*i+2] = q.z; rs[4*i+3] = q.w;
        }
        float kstep = (float)lane * (1.0f / 126.0f);
        float ph = 0.f;
        float a0 = 0.f, a1 = 0.f, a2 = 0.f, a3 = 0.f;
#pragma unroll
        for (int jj = 0; jj < NNODES; ++jj) {
            float cv = __builtin_amdgcn_cosf(ph);
            ph += kstep;
            ph = (ph >= 1.0f) ? ph - 1.0f : ph;
            float v = rs[jj] * cv;
            if ((jj & 3) == 0) a0 += v;
            else if ((jj & 3) == 1) a1 += v;
            else if ((jj & 3) == 2) a2 += v;
            else a3 += v;
        }
        float e = ((a0 + a1) + (a2 + a3)) * (2.0f / 63.0f);
        if (lane == 0 || lane == M_DEG) e *= 0.5f;
        C_lds[lane] = e;
    }
    __syncthreads();

    // ===================== per-point phase ==================================
    // bc constants (LDS broadcast), coefficients -> SGPRs via readfirstlane
    float lbw  = bc_lds[0] * bc_lds[0];
    float lbwx = bc_lds[1] * bc_lds[1];
    float rbM  = bc_lds[7] * bc_lds[7];
    float rbw  = bc_lds[5] * bc_lds[5];
    float e[NNODES];
#pragma unroll
    for (int k = 0; k < NNODES; ++k) {
        int bits = __builtin_amdgcn_readfirstlane(__float_as_int(C_lds[k]));
        e[k] = __int_as_float(bits);
    }

    size_t gtid = (size_t)blockIdx.x * blockDim.x + tid;
    size_t gstride = (size_t)gridDim.x * blockDim.x;

    // fused BC fills (regions 1..4); stores drain under the Clenshaw compute
    fill_region(out + (size_t)1 * N + 1, lbw,  (size_t)N, gtid, gstride);
    fill_region(out + (size_t)2 * N + 1, lbwx, (size_t)N, gtid, gstride);
    fill_region(out + (size_t)3 * N + 1, rbM,  (size_t)N, gtid, gstride);
    fill_region(out + (size_t)4 * N + 1, rbw,  (size_t)N, gtid, gstride);

    v2f accA = {0.f, 0.f}, accB = {0.f, 0.f};
    int i0 = (int)gtid;
    int gsz = (int)gstride;
    int n4 = N >> 2;
    const float4* x4 = reinterpret_cast<const float4*>(x);
    for (int i = i0; i < n4; i += gsz) {
        float4 xv4 = x4[i];
        v2f tA = {2.f * xv4.x - 1.f, 2.f * xv4.y - 1.f};
        v2f tB = {2.f * xv4.z - 1.f, 2.f * xv4.w - 1.f};
        v2f t2A = tA + tA, t2B = tB + tB;
        v2f b0A = {0.f, 0.f}, b1A = {0.f, 0.f};
        v2f b0B = {0.f, 0.f}, b1B = {0.f, 0.f};
#pragma unroll
        for (int k = M_DEG; k >= 1; --k) {
            v2f ek = {e[k], e[k]};
            v2f bnA = __builtin_elementwise_fma(t2A, b0A, ek) - b1A;
            b1A = b0A; b0A = bnA;
            v2f bnB = __builtin_elementwise_fma(t2B, b0B, ek) - b1B;
            b1B = b0B; b0B = bnB;
        }
        v2f e0 = {e[0], e[0]};
        v2f rA = __builtin_elementwise_fma(tA, b0A, e0) - b1A;
        v2f rB = __builtin_elementwise_fma(tB, b0B, e0) - b1B;
        accA = __builtin_elementwise_fma(rA, rA, accA);
        accB = __builtin_elementwise_fma(rB, rB, accB);
    }
    float accs = (accA.x + accA.y) + (accB.x + accB.y);
    for (int i = (n4 << 2) + i0; i < N; i += gsz) {   // tail (N % 4)
        float t = 2.f * x[i] - 1.f, t2 = t + t;
        float b0 = 0.f, b1 = 0.f;
#pragma unroll
        for (int k = M_DEG; k >= 1; --k) {
            float bn = fmaf(t2, b0, e[k]) - b1;
            b1 = b0; b0 = bn;
        }
        float r = fmaf(t, b0, e[0]) - b1;
        accs = fmaf(r, r, accs);
    }

    double a = (double)accs;
#pragma unroll
    for (int off = 32; off > 0; off >>= 1) a += __shfl_down(a, off, 64);
    __shared__ double red[4];
    if ((tid & 63) == 0) red[tid >> 6] = a;
    __syncthreads();
    if (tid == 0) partials[blockIdx.x] = red[0] + red[1] + red[2] + red[3];
}

// ---- K2: every block redundantly reduces partials (fixed order ->
// deterministic, identical result), computes loss, fills region 0 ------------
__global__ void __launch_bounds__(256)
pinn_loss(const double* __restrict__ partials, int nparts,
          const float* __restrict__ bc, float* __restrict__ out, int N) {
    int tid = threadIdx.x;
    double a = 0.0;
    for (int i = tid; i < nparts; i += 256) a += partials[i];
#pragma unroll
    for (int off = 32; off > 0; off >>= 1) a += __shfl_down(a, off, 64);
    __shared__ double red[4];
    if ((tid & 63) == 0) red[tid >> 6] = a;
    __syncthreads();
    double total = red[0] + red[1] + red[2] + red[3];   // same in every thread
    float pdef = (float)(total / (double)N);
    float lbw  = bc[0] * bc[0];
    float lbwx = bc[1] * bc[1];
    float rbM  = bc[7] * bc[7];
    float rbw  = bc[5] * bc[5];
    float loss = pdef + lbw + lbwx + rbM + rbw;         // reference add order

    size_t gtid = (size_t)blockIdx.x * blockDim.x + tid;
    size_t gstride = (size_t)gridDim.x * blockDim.x;
    fill_region(out, loss, (size_t)N, gtid, gstride);
    if (blockIdx.x == 0 && tid == 0) out[N] = pdef;     // pde_loss scalar
}

extern "C" void kernel_launch(void* const* d_in, const int* in_sizes, int n_in,
                              void* d_out, int out_size, void* d_ws, size_t ws_size,
                              hipStream_t stream) {
    const float* x  = (const float*)d_in[0];
    const float* W1 = (const float*)d_in[1];
    const float* b1 = (const float*)d_in[2];
    const float* W2 = (const float*)d_in[3];
    const float* b2 = (const float*)d_in[4];
    const float* W3 = (const float*)d_in[5];
    const float* b3 = (const float*)d_in[6];
    const float* W4 = (const float*)d_in[7];
    const float* b4 = (const float*)d_in[8];
    float* out = (float*)d_out;
    int N = in_sizes[0];

    // ws layout: bc[10] @256B | partials @1024B
    float*  bc       = (float*)((char*)d_ws + 256);
    double* partials = (double*)((char*)d_ws + 1024);

    int NB = 512;
    size_t need = 1024 + (size_t)NB * 8;
    if (ws_size < need) {
        NB = (int)((ws_size > 1024 + 8) ? (ws_size - 1024) / 8 : 1);
        if (NB < 1) NB = 1;
        if (NB > 512) NB = 512;
    }

    hipLaunchKernelGGL(pinn_main, dim3(NB), dim3(256), 0, stream,
                       x, W1, b1, W2, b2, W3, b3, W4, b4,
                       out, bc, partials, N);
    int gx = (N / 4 + 255) / 256;
    if (gx > 512) gx = 512;
    if (gx < 1) gx = 1;
    hipLaunchKernelGGL(pinn_loss, dim3(gx), dim3(256), 0, stream,
                       partials, NB, bc, out, N);
}

// Round 11
// 28.323 us; speedup vs baseline: 1.6911x; 1.0435x over previous
//
#include <hip/hip_runtime.h>
#include <math.h>

#define DH 15
#define NNODES 64           // Chebyshev-Lobatto nodes, degree 63
#define M_DEG  63

typedef float v2f __attribute__((ext_vector_type(2)));

// ---- stable tanh + derivative factors -------------------------------------
__device__ __forceinline__ void tanh_fs(float u0, float& t, float& s,
                                        float& f2, float& f3, float& f4) {
    float e = __builtin_amdgcn_exp2f(u0 * 2.885390081777927f); // exp(2*u0)
    float r = __builtin_amdgcn_rcpf(1.0f + e);
    t = 1.0f - 2.0f * r;
    s = 4.0f * r * (1.0f - r);
    f2 = -2.0f * t * s;
    f3 = s * (4.0f * t * t - 2.0f * s);
    f4 = 8.0f * t * s * (2.0f * s - t * t);
}

__device__ __forceinline__ void tanh_jet(float u0, float u1, float u2,
                                         float u3, float u4, float h[5]) {
    float t, s, f2, f3, f4;
    tanh_fs(u0, t, s, f2, f3, f4);
    float u1s = u1 * u1;
    h[0] = t;
    h[1] = s * u1;
    h[2] = f2 * u1s + s * u2;
    h[3] = f3 * u1s * u1 + 3.0f * f2 * u1 * u2 + s * u3;
    h[4] = f4 * u1s * u1s + 6.0f * f3 * u1s * u2
         + f2 * (3.0f * u2 * u2 + 4.0f * u1 * u3) + s * u4;
}

// ---- helper: grid-stride constant fill of one [N] region --------------------
__device__ __forceinline__ void fill_region(float* __restrict__ p, float c,
                                            size_t n, size_t tid, size_t stride) {
    size_t head = ((16 - ((size_t)p & 15)) & 15) >> 2;  // floats to 16B align
    if (head > n) head = n;
    if (tid < head) p[tid] = c;
    size_t n4 = (n - head) >> 2;
    float4* p4 = reinterpret_cast<float4*>(p + head);
    float4 cv = {c, c, c, c};
    for (size_t i = tid; i < n4; i += stride) p4[i] = cv;
    size_t t = head + (n4 << 2) + tid;
    if (t < n) p[t] = c;
}

// ---- K1: x-prefetch -> redundant 4-wave node eval + DCT -> Clenshaw sum -----
// No fills here: pure compute. x loads are issued BEFORE the nodes phase so
// their HBM latency hides under it.
__global__ void __launch_bounds__(256)
pinn_pde(const float* __restrict__ x,
         const float* __restrict__ W1, const float* __restrict__ b1,
         const float* __restrict__ W2, const float* __restrict__ b2,
         const float* __restrict__ W3, const float* __restrict__ b3,
         const float* __restrict__ W4, const float* __restrict__ b4,
         float* __restrict__ bcg, double* __restrict__ partials, int N) {
    __shared__ float hs[DH][5][NNODES];
    __shared__ alignas(16) float rsh[NNODES];
    __shared__ float C_lds[NNODES];
    const int tid  = threadIdx.x;
    const int lane = tid & 63;           // node index
    const int wq   = tid >> 6;           // j-quad (wave-uniform)

    // ---- prefetch this thread's x (≤4 float4) before the nodes phase -------
    int i0 = blockIdx.x * blockDim.x + tid;
    int gsz = gridDim.x * blockDim.x;
    int n4 = N >> 2;
    const float4* x4 = reinterpret_cast<const float4*>(x);
    float4 px[4];
    bool pv[4];
#pragma unroll
    for (int m = 0; m < 4; ++m) {
        int ii = i0 + m * gsz;
        pv[m] = (ii < n4);
        px[m] = pv[m] ? x4[ii] : float4{0.f, 0.f, 0.f, 0.f};
    }

    // ===================== nodes phase (every block) =========================
    float xv;
    if (lane == 0)           xv = 1.0f;
    else if (lane == M_DEG)  xv = 0.0f;
    else xv = 0.5f + 0.5f * __builtin_amdgcn_cosf((float)lane * (1.0f / 126.0f));

    // layer 1: each wave computes its 4 neurons
#pragma unroll
    for (int jj = 0; jj < 4; ++jj) {
        int j = wq * 4 + jj;
        if (j < DH) {
            float w = W1[j];
            float t, s, f2, f3, f4;
            tanh_fs(fmaf(xv, w, b1[j]), t, s, f2, f3, f4);
            float w2 = w * w;
            hs[j][0][lane] = t;
            hs[j][1][lane] = s * w;
            hs[j][2][lane] = f2 * w2;
            hs[j][3][lane] = f3 * w2 * w;
            hs[j][4][lane] = f4 * w2 * w2;
        }
    }
    __syncthreads();

    // layers 2 and 3
    const float* Ws[2] = {W2, W3};
    const float* Bs[2] = {b2, b3};
#pragma unroll
    for (int L = 0; L < 2; ++L) {
        const float* W = Ws[L];
        const float* B = Bs[L];
        float u[4][5];
#pragma unroll
        for (int jj = 0; jj < 4; ++jj)
#pragma unroll
            for (int c = 0; c < 5; ++c) u[jj][c] = 0.f;
#pragma unroll
        for (int k = 0; k < DH; ++k) {
            float g0 = hs[k][0][lane], g1 = hs[k][1][lane], g2 = hs[k][2][lane],
                  g3 = hs[k][3][lane], g4 = hs[k][4][lane];
#pragma unroll
            for (int jj = 0; jj < 4; ++jj) {
                int j = wq * 4 + jj;
                float w = (j < DH) ? W[k * DH + j] : 0.f;
                u[jj][0] = fmaf(g0, w, u[jj][0]);
                u[jj][1] = fmaf(g1, w, u[jj][1]);
                u[jj][2] = fmaf(g2, w, u[jj][2]);
                u[jj][3] = fmaf(g3, w, u[jj][3]);
                u[jj][4] = fmaf(g4, w, u[jj][4]);
            }
        }
        __syncthreads();
#pragma unroll
        for (int jj = 0; jj < 4; ++jj) {
            int j = wq * 4 + jj;
            if (j < DH) {
                float hj[5];
                tanh_jet(u[jj][0] + B[j], u[jj][1], u[jj][2], u[jj][3],
                         u[jj][4], hj);
                hs[j][0][lane] = hj[0]; hs[j][1][lane] = hj[1];
                hs[j][2][lane] = hj[2]; hs[j][3][lane] = hj[3];
                hs[j][4][lane] = hj[4];
            }
        }
        __syncthreads();
    }

    // output layer + residual + DCT: wave 0 only
    if (wq == 0) {
        float o0 = b4[0], o1 = 0.f, o2 = 0.f, o3 = 0.f, o4 = 0.f;
#pragma unroll
        for (int k = 0; k < DH; ++k) {
            float w = W4[k];
            o0 = fmaf(hs[k][0][lane], w, o0);
            o1 = fmaf(hs[k][1][lane], w, o1);
            o2 = fmaf(hs[k][2][lane], w, o2);
            o3 = fmaf(hs[k][3][lane], w, o3);
            o4 = fmaf(hs[k][4][lane], w, o4);
        }
        rsh[lane] = ((lane == 0 || lane == M_DEG) ? 0.5f : 1.0f) * (o4 + 1.0f);
        if (blockIdx.x == 0) {
            if (lane == M_DEG) {              // x = 0 (left)
                bcg[0] = o0; bcg[1] = o1; bcg[2] = o2; bcg[3] = o3; bcg[4] = o4;
            }
            if (lane == 0) {                  // x = 1 (right)
                bcg[5] = o0; bcg[6] = o1; bcg[7] = o2; bcg[8] = o3; bcg[9] = o4;
            }
        }
        __builtin_amdgcn_s_waitcnt(0);  // wave-level fence on rsh

        // DCT-I, v_cos in revolutions, phase accumulation w/ conditional wrap
        float rs[NNODES];
#pragma unroll
        for (int i = 0; i < NNODES / 4; ++i) {
            float4 q = *reinterpret_cast<const float4*>(&rsh[4 * i]);
            rs[4*i] = q.x; rs[4*i+1] = q.y; rs[4*i+2] = q.z; rs[4*i+3] = q.w;
        }
        float kstep = (float)lane * (1.0f / 126.0f);
        float ph = 0.f;
        float a0 = 0.f, a1 = 0.f, a2 = 0.f, a3 = 0.f;
#pragma unroll
        for (int jj = 0; jj < NNODES; ++jj) {
            float cv = __builtin_amdgcn_cosf(ph);
            ph += kstep;
            ph = (ph >= 1.0f) ? ph - 1.0f : ph;
            float v = rs[jj] * cv;
            if ((jj & 3) == 0) a0 += v;
            else if ((jj & 3) == 1) a1 += v;
            else if ((jj & 3) == 2) a2 += v;
            else a3 += v;
        }
        float e = ((a0 + a1) + (a2 + a3)) * (2.0f / 63.0f);
        if (lane == 0 || lane == M_DEG) e *= 0.5f;
        C_lds[lane] = e;
    }
    __syncthreads();

    // ===================== per-point Clenshaw ===============================
    // coefficients -> SGPRs via readfirstlane (wave-uniform values)
    float e[NNODES];
#pragma unroll
    for (int k = 0; k < NNODES; ++k) {
        int bits = __builtin_amdgcn_readfirstlane(__float_as_int(C_lds[k]));
        e[k] = __int_as_float(bits);
    }

    v2f accA = {0.f, 0.f}, accB = {0.f, 0.f};
#pragma unroll
    for (int m = 0; m < 4; ++m) {
        if (pv[m]) {
            float4 xv4 = px[m];
            v2f tA = {2.f * xv4.x - 1.f, 2.f * xv4.y - 1.f};
            v2f tB = {2.f * xv4.z - 1.f, 2.f * xv4.w - 1.f};
            v2f t2A = tA + tA, t2B = tB + tB;
            v2f b0A = {0.f, 0.f}, b1A = {0.f, 0.f};
            v2f b0B = {0.f, 0.f}, b1B = {0.f, 0.f};
#pragma unroll
            for (int k = M_DEG; k >= 1; --k) {
                v2f ek = {e[k], e[k]};
                v2f bnA = __builtin_elementwise_fma(t2A, b0A, ek) - b1A;
                b1A = b0A; b0A = bnA;
                v2f bnB = __builtin_elementwise_fma(t2B, b0B, ek) - b1B;
                b1B = b0B; b0B = bnB;
            }
            v2f e0 = {e[0], e[0]};
            v2f rA = __builtin_elementwise_fma(tA, b0A, e0) - b1A;
            v2f rB = __builtin_elementwise_fma(tB, b0B, e0) - b1B;
            accA = __builtin_elementwise_fma(rA, rA, accA);
            accB = __builtin_elementwise_fma(rB, rB, accB);
        }
    }
    // generic residual iterations (if grid was shrunk by ws fallback)
    for (int i = i0 + 4 * gsz; i < n4; i += gsz) {
        float4 xv4 = x4[i];
        v2f tA = {2.f * xv4.x - 1.f, 2.f * xv4.y - 1.f};
        v2f tB = {2.f * xv4.z - 1.f, 2.f * xv4.w - 1.f};
        v2f t2A = tA + tA, t2B = tB + tB;
        v2f b0A = {0.f, 0.f}, b1A = {0.f, 0.f};
        v2f b0B = {0.f, 0.f}, b1B = {0.f, 0.f};
#pragma unroll
        for (int k = M_DEG; k >= 1; --k) {
            v2f ek = {e[k], e[k]};
            v2f bnA = __builtin_elementwise_fma(t2A, b0A, ek) - b1A;
            b1A = b0A; b0A = bnA;
            v2f bnB = __builtin_elementwise_fma(t2B, b0B, ek) - b1B;
            b1B = b0B; b0B = bnB;
        }
        v2f e0 = {e[0], e[0]};
        v2f rA = __builtin_elementwise_fma(tA, b0A, e0) - b1A;
        v2f rB = __builtin_elementwise_fma(tB, b0B, e0) - b1B;
        accA = __builtin_elementwise_fma(rA, rA, accA);
        accB = __builtin_elementwise_fma(rB, rB, accB);
    }
    float accs = (accA.x + accA.y) + (accB.x + accB.y);
    for (int i = (n4 << 2) + i0; i < N; i += gsz) {   // tail (N % 4)
        float t = 2.f * x[i] - 1.f, t2 = t + t;
        float b0 = 0.f, b1 = 0.f;
#pragma unroll
        for (int k = M_DEG; k >= 1; --k) {
            float bn = fmaf(t2, b0, e[k]) - b1;
            b1 = b0; b0 = bn;
        }
        float r = fmaf(t, b0, e[0]) - b1;
        accs = fmaf(r, r, accs);
    }

    double a = (double)accs;
#pragma unroll
    for (int off = 32; off > 0; off >>= 1) a += __shfl_down(a, off, 64);
    __shared__ double red[4];
    if ((tid & 63) == 0) red[tid >> 6] = a;
    __syncthreads();
    if (tid == 0) partials[blockIdx.x] = red[0] + red[1] + red[2] + red[3];
}

// ---- K2: all fills + redundant deterministic reduce -------------------------
// BC fills (regions 1-4) are issued first (only need bc); the fixed-order
// partials reduce runs while those stores drain; then region 0 (loss).
__global__ void __launch_bounds__(256)
pinn_out(const double* __restrict__ partials, int nparts,
         const float* __restrict__ bc, float* __restrict__ out, int N) {
    int tid = threadIdx.x;
    float c0 = bc[0], c1 = bc[1], c7 = bc[7], c5 = bc[5];  // uniform -> SGPR
    float lbw  = c0 * c0;
    float lbwx = c1 * c1;
    float rbM  = c7 * c7;
    float rbw  = c5 * c5;

    size_t gtid = (size_t)blockIdx.x * blockDim.x + tid;
    size_t gstride = (size_t)gridDim.x * blockDim.x;
    fill_region(out + (size_t)1 * N + 1, lbw,  (size_t)N, gtid, gstride);
    fill_region(out + (size_t)2 * N + 1, lbwx, (size_t)N, gtid, gstride);
    fill_region(out + (size_t)3 * N + 1, rbM,  (size_t)N, gtid, gstride);
    fill_region(out + (size_t)4 * N + 1, rbw,  (size_t)N, gtid, gstride);

    // redundant fixed-order reduce (identical, deterministic in every block)
    double a = 0.0;
    for (int i = tid; i < nparts; i += 256) a += partials[i];
#pragma unroll
    for (int off = 32; off > 0; off >>= 1) a += __shfl_down(a, off, 64);
    __shared__ double red[4];
    if ((tid & 63) == 0) red[tid >> 6] = a;
    __syncthreads();
    double total = red[0] + red[1] + red[2] + red[3];
    float pdef = (float)(total / (double)N);
    float loss = pdef + lbw + lbwx + rbM + rbw;   // reference add order

    fill_region(out, loss, (size_t)N, gtid, gstride);
    if (blockIdx.x == 0 && tid == 0) out[N] = pdef;   // pde_loss scalar
}

extern "C" void kernel_launch(void* const* d_in, const int* in_sizes, int n_in,
                              void* d_out, int out_size, void* d_ws, size_t ws_size,
                              hipStream_t stream) {
    const float* x  = (const float*)d_in[0];
    const float* W1 = (const float*)d_in[1];
    const float* b1 = (const float*)d_in[2];
    const float* W2 = (const float*)d_in[3];
    const float* b2 = (const float*)d_in[4];
    const float* W3 = (const float*)d_in[5];
    const float* b3 = (const float*)d_in[6];
    const float* W4 = (const float*)d_in[7];
    const float* b4 = (const float*)d_in[8];
    float* out = (float*)d_out;
    int N = in_sizes[0];

    // ws layout: bc[10] @256B | partials @1024B
    float*  bc       = (float*)((char*)d_ws + 256);
    double* partials = (double*)((char*)d_ws + 1024);

    int NB = 512;
    size_t need = 1024 + (size_t)NB * 8;
    if (ws_size < need) {
        NB = (int)((ws_size > 1024 + 8) ? (ws_size - 1024) / 8 : 1);
        if (NB < 1) NB = 1;
        if (NB > 512) NB = 512;
    }

    hipLaunchKernelGGL(pinn_pde, dim3(NB), dim3(256), 0, stream,
                       x, W1, b1, W2, b2, W3, b3, W4, b4, bc, partials, N);
    hipLaunchKernelGGL(pinn_out, dim3(512), dim3(256), 0, stream,
                       partials, NB, bc, out, N);
}

// Round 13
// 28.230 us; speedup vs baseline: 1.6966x; 1.0033x over previous
//
#include <hip/hip_runtime.h>
#include <math.h>

#define DH 15
#define NNODES 64           // Chebyshev-Lobatto nodes, degree 63
#define M_DEG  63

typedef float v2f __attribute__((ext_vector_type(2)));

// ---- stable tanh + derivative factors -------------------------------------
__device__ __forceinline__ void tanh_fs(float u0, float& t, float& s,
                                        float& f2, float& f3, float& f4) {
    float e = __builtin_amdgcn_exp2f(u0 * 2.885390081777927f); // exp(2*u0)
    float r = __builtin_amdgcn_rcpf(1.0f + e);
    t = 1.0f - 2.0f * r;
    s = 4.0f * r * (1.0f - r);
    f2 = -2.0f * t * s;
    f3 = s * (4.0f * t * t - 2.0f * s);
    f4 = 8.0f * t * s * (2.0f * s - t * t);
}

__device__ __forceinline__ void tanh_jet(float u0, float u1, float u2,
                                         float u3, float u4, float h[5]) {
    float t, s, f2, f3, f4;
    tanh_fs(u0, t, s, f2, f3, f4);
    float u1s = u1 * u1;
    h[0] = t;
    h[1] = s * u1;
    h[2] = f2 * u1s + s * u2;
    h[3] = f3 * u1s * u1 + 3.0f * f2 * u1 * u2 + s * u3;
    h[4] = f4 * u1s * u1s + 6.0f * f3 * u1s * u2
         + f2 * (3.0f * u2 * u2 + 4.0f * u1 * u3) + s * u4;
}

// ---- helper: grid-stride constant fill of one [N] region --------------------
__device__ __forceinline__ void fill_region(float* __restrict__ p, float c,
                                            size_t n, size_t tid, size_t stride) {
    size_t head = ((16 - ((size_t)p & 15)) & 15) >> 2;  // floats to 16B align
    if (head > n) head = n;
    if (tid < head) p[tid] = c;
    size_t n4 = (n - head) >> 2;
    float4* p4 = reinterpret_cast<float4*>(p + head);
    float4 cv = {c, c, c, c};
    for (size_t i = tid; i < n4; i += stride) p4[i] = cv;
    size_t t = head + (n4 << 2) + tid;
    if (t < n) p[t] = c;
}

// ---- K1: x-prefetch -> redundant node eval + DCT -> BC fills -> Clenshaw ----
// BC fills (32 MB) are issued between the nodes phase and the Clenshaw loop so
// their store drain overlaps the remaining VALU work.
__global__ void __launch_bounds__(256)
pinn_pde(const float* __restrict__ x,
         const float* __restrict__ W1, const float* __restrict__ b1,
         const float* __restrict__ W2, const float* __restrict__ b2,
         const float* __restrict__ W3, const float* __restrict__ b3,
         const float* __restrict__ W4, const float* __restrict__ b4,
         float* __restrict__ out, float* __restrict__ bcg,
         double* __restrict__ partials, int N) {
    __shared__ float hs[DH][5][NNODES];
    __shared__ alignas(16) float rsh[NNODES];
    __shared__ float C_lds[NNODES];
    __shared__ float bc_lds[10];
    const int tid  = threadIdx.x;
    const int lane = tid & 63;           // node index
    const int wq   = tid >> 6;           // j-quad (wave-uniform)

    // ---- prefetch this thread's x (≤4 float4) before the nodes phase -------
    int i0 = blockIdx.x * blockDim.x + tid;
    int gsz = gridDim.x * blockDim.x;
    int n4 = N >> 2;
    const float4* x4 = reinterpret_cast<const float4*>(x);
    float4 px[4];
    bool pv[4];
#pragma unroll
    for (int m = 0; m < 4; ++m) {
        int ii = i0 + m * gsz;
        pv[m] = (ii < n4);
        px[m] = pv[m] ? x4[ii] : float4{0.f, 0.f, 0.f, 0.f};
    }

    // ===================== nodes phase (every block) =========================
    float xv;
    if (lane == 0)           xv = 1.0f;
    else if (lane == M_DEG)  xv = 0.0f;
    else xv = 0.5f + 0.5f * __builtin_amdgcn_cosf((float)lane * (1.0f / 126.0f));

#pragma unroll
    for (int jj = 0; jj < 4; ++jj) {     // layer 1: 4 neurons per wave
        int j = wq * 4 + jj;
        if (j < DH) {
            float w = W1[j];
            float t, s, f2, f3, f4;
            tanh_fs(fmaf(xv, w, b1[j]), t, s, f2, f3, f4);
            float w2 = w * w;
            hs[j][0][lane] = t;
            hs[j][1][lane] = s * w;
            hs[j][2][lane] = f2 * w2;
            hs[j][3][lane] = f3 * w2 * w;
            hs[j][4][lane] = f4 * w2 * w2;
        }
    }
    __syncthreads();

    const float* Ws[2] = {W2, W3};       // layers 2 and 3
    const float* Bs[2] = {b2, b3};
#pragma unroll
    for (int L = 0; L < 2; ++L) {
        const float* W = Ws[L];
        const float* B = Bs[L];
        float u[4][5];
#pragma unroll
        for (int jj = 0; jj < 4; ++jj)
#pragma unroll
            for (int c = 0; c < 5; ++c) u[jj][c] = 0.f;
#pragma unroll
        for (int k = 0; k < DH; ++k) {
            float g0 = hs[k][0][lane], g1 = hs[k][1][lane], g2 = hs[k][2][lane],
                  g3 = hs[k][3][lane], g4 = hs[k][4][lane];
#pragma unroll
            for (int jj = 0; jj < 4; ++jj) {
                int j = wq * 4 + jj;
                float w = (j < DH) ? W[k * DH + j] : 0.f;
                u[jj][0] = fmaf(g0, w, u[jj][0]);
                u[jj][1] = fmaf(g1, w, u[jj][1]);
                u[jj][2] = fmaf(g2, w, u[jj][2]);
                u[jj][3] = fmaf(g3, w, u[jj][3]);
                u[jj][4] = fmaf(g4, w, u[jj][4]);
            }
        }
        __syncthreads();
#pragma unroll
        for (int jj = 0; jj < 4; ++jj) {
            int j = wq * 4 + jj;
            if (j < DH) {
                float hj[5];
                tanh_jet(u[jj][0] + B[j], u[jj][1], u[jj][2], u[jj][3],
                         u[jj][4], hj);
                hs[j][0][lane] = hj[0]; hs[j][1][lane] = hj[1];
                hs[j][2][lane] = hj[2]; hs[j][3][lane] = hj[3];
                hs[j][4][lane] = hj[4];
            }
        }
        __syncthreads();
    }

    // output layer + residual + DCT: wave 0 only
    if (wq == 0) {
        float o0 = b4[0], o1 = 0.f, o2 = 0.f, o3 = 0.f, o4 = 0.f;
#pragma unroll
        for (int k = 0; k < DH; ++k) {
            float w = W4[k];
            o0 = fmaf(hs[k][0][lane], w, o0);
            o1 = fmaf(hs[k][1][lane], w, o1);
            o2 = fmaf(hs[k][2][lane], w, o2);
            o3 = fmaf(hs[k][3][lane], w, o3);
            o4 = fmaf(hs[k][4][lane], w, o4);
        }
        rsh[lane] = ((lane == 0 || lane == M_DEG) ? 0.5f : 1.0f) * (o4 + 1.0f);
        if (lane == M_DEG) {                  // x = 0 (left)
            bc_lds[0] = o0; bc_lds[1] = o1; bc_lds[2] = o2;
            bc_lds[3] = o3; bc_lds[4] = o4;
            if (blockIdx.x == 0) {
                bcg[0] = o0; bcg[1] = o1; bcg[2] = o2; bcg[3] = o3; bcg[4] = o4;
            }
        }
        if (lane == 0) {                      // x = 1 (right)
            bc_lds[5] = o0; bc_lds[6] = o1; bc_lds[7] = o2;
            bc_lds[8] = o3; bc_lds[9] = o4;
            if (blockIdx.x == 0) {
                bcg[5] = o0; bcg[6] = o1; bcg[7] = o2; bcg[8] = o3; bcg[9] = o4;
            }
        }
        __builtin_amdgcn_s_waitcnt(0);  // wave-level fence on rsh

        // DCT-I, v_cos in revolutions, phase accumulation w/ conditional wrap
        float rs[NNODES];
#pragma unroll
        for (int i = 0; i < NNODES / 4; ++i) {
            float4 q = *reinterpret_cast<const float4*>(&rsh[4 * i]);
            rs[4*i] = q.x; rs[4*i+1] = q.y; rs[4*i+2] = q.z; rs[4*i+3] = q.w;
        }
        float kstep = (float)lane * (1.0f / 126.0f);
        float ph = 0.f;
        float a0 = 0.f, a1 = 0.f, a2 = 0.f, a3 = 0.f;
#pragma unroll
        for (int jj = 0; jj < NNODES; ++jj) {
            float cv = __builtin_amdgcn_cosf(ph);
            ph += kstep;
            ph = (ph >= 1.0f) ? ph - 1.0f : ph;
            float v = rs[jj] * cv;
            if ((jj & 3) == 0) a0 += v;
            else if ((jj & 3) == 1) a1 += v;
            else if ((jj & 3) == 2) a2 += v;
            else a3 += v;
        }
        float e = ((a0 + a1) + (a2 + a3)) * (2.0f / 63.0f);
        if (lane == 0 || lane == M_DEG) e *= 0.5f;
        C_lds[lane] = e;
    }
    __syncthreads();

    // ===================== BC fills (32 MB), before Clenshaw =================
    float lbw  = bc_lds[0] * bc_lds[0];
    float lbwx = bc_lds[1] * bc_lds[1];
    float rbM  = bc_lds[7] * bc_lds[7];
    float rbw  = bc_lds[5] * bc_lds[5];
    size_t gtid = (size_t)i0;
    size_t gstride = (size_t)gsz;
    fill_region(out + (size_t)1 * N + 1, lbw,  (size_t)N, gtid, gstride);
    fill_region(out + (size_t)2 * N + 1, lbwx, (size_t)N, gtid, gstride);
    fill_region(out + (size_t)3 * N + 1, rbM,  (size_t)N, gtid, gstride);
    fill_region(out + (size_t)4 * N + 1, rbw,  (size_t)N, gtid, gstride);

    // ===================== per-point Clenshaw ===============================
    float e[NNODES];
#pragma unroll
    for (int k = 0; k < NNODES; ++k) {
        int bits = __builtin_amdgcn_readfirstlane(__float_as_int(C_lds[k]));
        e[k] = __int_as_float(bits);
    }

    v2f accA = {0.f, 0.f}, accB = {0.f, 0.f};
#pragma unroll
    for (int m = 0; m < 4; ++m) {
        if (pv[m]) {
            float4 xv4 = px[m];
            v2f tA = {2.f * xv4.x - 1.f, 2.f * xv4.y - 1.f};
            v2f tB = {2.f * xv4.z - 1.f, 2.f * xv4.w - 1.f};
            v2f t2A = tA + tA, t2B = tB + tB;
            v2f b0A = {0.f, 0.f}, b1A = {0.f, 0.f};
            v2f b0B = {0.f, 0.f}, b1B = {0.f, 0.f};
#pragma unroll
            for (int k = M_DEG; k >= 1; --k) {
                v2f ek = {e[k], e[k]};
                v2f bnA = __builtin_elementwise_fma(t2A, b0A, ek) - b1A;
                b1A = b0A; b0A = bnA;
                v2f bnB = __builtin_elementwise_fma(t2B, b0B, ek) - b1B;
                b1B = b0B; b0B = bnB;
            }
            v2f e0 = {e[0], e[0]};
            v2f rA = __builtin_elementwise_fma(tA, b0A, e0) - b1A;
            v2f rB = __builtin_elementwise_fma(tB, b0B, e0) - b1B;
            accA = __builtin_elementwise_fma(rA, rA, accA);
            accB = __builtin_elementwise_fma(rB, rB, accB);
        }
    }
    for (int i = i0 + 4 * gsz; i < n4; i += gsz) {  // if grid was shrunk
        float4 xv4 = x4[i];
        v2f tA = {2.f * xv4.x - 1.f, 2.f * xv4.y - 1.f};
        v2f tB = {2.f * xv4.z - 1.f, 2.f * xv4.w - 1.f};
        v2f t2A = tA + tA, t2B = tB + tB;
        v2f b0A = {0.f, 0.f}, b1A = {0.f, 0.f};
        v2f b0B = {0.f, 0.f}, b1B = {0.f, 0.f};
#pragma unroll
        for (int k = M_DEG; k >= 1; --k) {
            v2f ek = {e[k], e[k]};
            v2f bnA = __builtin_elementwise_fma(t2A, b0A, ek) - b1A;
            b1A = b0A; b0A = bnA;
            v2f bnB = __builtin_elementwise_fma(t2B, b0B, ek) - b1B;
            b1B = b0B; b0B = bnB;
        }
        v2f e0 = {e[0], e[0]};
        v2f rA = __builtin_elementwise_fma(tA, b0A, e0) - b1A;
        v2f rB = __builtin_elementwise_fma(tB, b0B, e0) - b1B;
        accA = __builtin_elementwise_fma(rA, rA, accA);
        accB = __builtin_elementwise_fma(rB, rB, accB);
    }
    float accs = (accA.x + accA.y) + (accB.x + accB.y);
    for (int i = (n4 << 2) + i0; i < N; i += gsz) {   // tail (N % 4)
        float t = 2.f * x[i] - 1.f, t2 = t + t;
        float b0 = 0.f, b1 = 0.f;
#pragma unroll
        for (int k = M_DEG; k >= 1; --k) {
            float bn = fmaf(t2, b0, e[k]) - b1;
            b1 = b0; b0 = bn;
        }
        float r = fmaf(t, b0, e[0]) - b1;
        accs = fmaf(r, r, accs);
    }

    double a = (double)accs;
#pragma unroll
    for (int off = 32; off > 0; off >>= 1) a += __shfl_down(a, off, 64);
    __shared__ double red[4];
    if ((tid & 63) == 0) red[tid >> 6] = a;
    __syncthreads();
    if (tid == 0) partials[blockIdx.x] = red[0] + red[1] + red[2] + red[3];
}

// ---- K2: minimal — fixed-order reduce + 8 MB loss fill + scalar -------------
__global__ void __launch_bounds__(256)
pinn_out(const double* __restrict__ partials, int nparts,
         const float* __restrict__ bc, float* __restrict__ out, int N) {
    int tid = threadIdx.x;
    float c0 = bc[0], c1 = bc[1], c7 = bc[7], c5 = bc[5];  // uniform -> SGPR
    float lbw  = c0 * c0;
    float lbwx = c1 * c1;
    float rbM  = c7 * c7;
    float rbw  = c5 * c5;

    // redundant fixed-order reduce (identical, deterministic in every block)
    double a = 0.0;
    for (int i = tid; i < nparts; i += 256) a += partials[i];
#pragma unroll
    for (int off = 32; off > 0; off >>= 1) a += __shfl_down(a, off, 64);
    __shared__ double red[4];
    if ((tid & 63) == 0) red[tid >> 6] = a;
    __syncthreads();
    double total = red[0] + red[1] + red[2] + red[3];
    float pdef = (float)(total / (double)N);
    float loss = pdef + lbw + lbwx + rbM + rbw;   // reference add order

    size_t gtid = (size_t)blockIdx.x * blockDim.x + tid;
    size_t gstride = (size_t)gridDim.x * blockDim.x;
    fill_region(out, loss, (size_t)N, gtid, gstride);
    if (blockIdx.x == 0 && tid == 0) out[N] = pdef;   // pde_loss scalar
}

extern "C" void kernel_launch(void* const* d_in, const int* in_sizes, int n_in,
                              void* d_out, int out_size, void* d_ws, size_t ws_size,
                              hipStream_t stream) {
    const float* x  = (const float*)d_in[0];
    const float* W1 = (const float*)d_in[1];
    const float* b1 = (const float*)d_in[2];
    const float* W2 = (const float*)d_in[3];
    const float* b2 = (const float*)d_in[4];
    const float* W3 = (const float*)d_in[5];
    const float* b3 = (const float*)d_in[6];
    const float* W4 = (const float*)d_in[7];
    const float* b4 = (const float*)d_in[8];
    float* out = (float*)d_out;
    int N = in_sizes[0];

    // ws layout: bc[10] @256B | partials @1024B
    float*  bc       = (float*)((char*)d_ws + 256);
    double* partials = (double*)((char*)d_ws + 1024);

    int NB = 512;
    size_t need = 1024 + (size_t)NB * 8;
    if (ws_size < need) {
        NB = (int)((ws_size > 1024 + 8) ? (ws_size - 1024) / 8 : 1);
        if (NB < 1) NB = 1;
        if (NB > 512) NB = 512;
    }

    hipLaunchKernelGGL(pinn_pde, dim3(NB), dim3(256), 0, stream,
                       x, W1, b1, W2, b2, W3, b3, W4, b4, out, bc, partials, N);
    hipLaunchKernelGGL(pinn_out, dim3(512), dim3(256), 0, stream,
                       partials, NB, bc, out, N);
}